// Round 3
// baseline (493.137 us; speedup 1.0000x reference)
//
#include <hip/hip_runtime.h>
#include <stdint.h>
#include <math.h>

#define NTOK (1024 * 256)   // B*L
#define P_DIM 300
#define P_PAD 320           // padded K for MFMA (multiple of 32)
#define P_LDS 328           // LDS row stride in bf16 elems (656B rows, 16B-aligned)
#define E_DIM 256

typedef __attribute__((ext_vector_type(8))) short bf16x8_t;
typedef __attribute__((ext_vector_type(4))) float f32x4_t;

__device__ __forceinline__ unsigned short f2b(float f) {
    union { float f; unsigned int i; } v; v.f = f;
    unsigned int x = v.i;
    return (unsigned short)((x + 0x7FFFu + ((x >> 16) & 1u)) >> 16);  // RNE f32->bf16
}

// K1: classify tokens (info = -cm for custom, ridx for regular), build compacted
// custom list, convert+pad lin_w [256,300] f32 -> [256,320] bf16
__global__ __launch_bounds__(256) void k1_classify(
        const int* __restrict__ x, const int* __restrict__ v2c,
        const int* __restrict__ v2r, const float* __restrict__ lin_w,
        int* __restrict__ info, int* __restrict__ list, int* __restrict__ counter,
        unsigned short* __restrict__ lin_w_pad) {
    int tid = threadIdx.x;
    int b = blockIdx.x;
    int t = b * 256 + tid;
    int xv = x[t];
    int cm = v2c[xv];                         // mask == (cm != 0)
    info[t] = (cm > 0) ? -cm : v2r[xv];
    if (cm > 0) {
        int pos = atomicAdd(counter, 1);
        list[pos] = t;
    }
    if (b < (E_DIM * P_PAD) / 256) {          // first 320 blocks fill padded lin_w
        int idx = b * 256 + tid;
        int e = idx / P_PAD;
        int k = idx - e * P_PAD;
        lin_w_pad[idx] = (k < P_DIM) ? f2b(lin_w[e * P_DIM + k]) : (unsigned short)0;
    }
}

// K2: regular tokens: out = lin_b + regular_w[ridx]  (custom rows written by K3)
// one wave per token, one float4 per lane (64 * 16B = full 1KB row)
__global__ __launch_bounds__(256) void k2_base(
        const int* __restrict__ info,
        const float* __restrict__ regular_w,
        const float* __restrict__ lin_b,
        float* __restrict__ out) {
    int tid = threadIdx.x;
    int lane = tid & 63;
    int wq = tid >> 6;
    float4 lb = *(const float4*)(lin_b + lane * 4);
    int base = blockIdx.x * 32;
    #pragma unroll
    for (int it = 0; it < 8; it++) {
        int t = base + wq * 8 + it;
        int inf = info[t];
        if (inf >= 0) {                       // wave-uniform branch (per token)
            float4 rf = *(const float4*)(regular_w + (size_t)inf * E_DIM + lane * 4);
            float4 o;
            o.x = rf.x + lb.x; o.y = rf.y + lb.y;
            o.z = rf.z + lb.z; o.w = rf.w + lb.w;
            *(float4*)(out + (size_t)t * E_DIM + lane * 4) = o;
        }
    }
}

// K3: fused Poincare-emb + MFMA GEMM over compacted custom tokens.
// Block = 256 thr (4 waves), tile = 32 tokens x 256 outputs.
// Phase 1: wave w computes emb (f32) for tokens w*8..w*8+7 -> bf16 into LDS.
// Phase 2: 16x16x32 bf16 MFMA, A from LDS, B (lin_w_pad bf16) from global.
__global__ __launch_bounds__(256) void k3_gemm(
        const int* __restrict__ list, const int* __restrict__ counter,
        const int* __restrict__ info, const int* __restrict__ v2r,
        const float* __restrict__ fixed_w,
        const float* __restrict__ train_w,
        const unsigned short* __restrict__ lin_w_pad,
        const float* __restrict__ regular_w,
        const float* __restrict__ lin_b,
        float* __restrict__ out) {
    __shared__ __align__(16) unsigned short semb[32][P_LDS];
    int count = counter[0];
    int i0 = blockIdx.x * 32;
    if (i0 >= count) return;                  // uniform per block; before any sync
    int tid = threadIdx.x;
    int wid = tid >> 6;
    int lane = tid & 63;

    // ---- Phase 1: embeddings into LDS ----
    for (int it = 0; it < 8; it++) {
        int i = i0 + wid * 8 + it;
        int iS = (i < count) ? i : (count - 1);   // clamp: dup rows never stored
        int t = list[iS];
        int cm = -info[t];                        // listed tokens have info = -cm
        const float* fw = fixed_w + (size_t)cm * P_DIM;
        const float* tw = train_w + (size_t)cm * P_DIM;
        float w[5], tr[5];
        float sw2 = 0.f, st2 = 0.f, swt = 0.f;
        #pragma unroll
        for (int s = 0; s < 5; s++) {
            int j = lane + 64 * s;
            float wv = 0.f, tv = 0.f;
            if (j < P_DIM) { wv = fw[j]; tv = tw[j]; }
            w[s] = wv; tr[s] = tv;
            sw2 = fmaf(wv, wv, sw2); st2 = fmaf(tv, tv, st2); swt = fmaf(wv, tv, swt);
        }
        #pragma unroll
        for (int m = 32; m >= 1; m >>= 1) {
            sw2 += __shfl_xor(sw2, m, 64);
            st2 += __shfl_xor(st2, m, 64);
            swt += __shfl_xor(swt, m, 64);
        }
        float norm = sqrtf(sw2);
        norm = fminf(norm, 0.9999999f);           // defensive: never fires on valid data
        float scale = (norm > 0.f) ? (atanhf(norm) / norm) : 1.0f;
        float x2 = scale * scale * sw2;           // ||logmap0(w)||^2
        float y2 = st2;
        float xy = scale * swt;                   // <logmap0(w), tr>
        float c1 = (1.f + 2.f * xy + y2) * scale; // coeff of w
        float c2 = (1.f - x2);                    // coeff of tr
        float den = fmaxf(1.f + 2.f * xy + x2 * y2, 1e-15f);
        float inv = 1.f / den;
        int tl = wid * 8 + it;
        #pragma unroll
        for (int s = 0; s < 5; s++) {
            int j = lane + 64 * s;                // covers 0..319
            float v = (j < P_DIM) ? (c1 * w[s] + c2 * tr[s]) * inv : 0.f;
            semb[tl][j] = f2b(v);
        }
    }
    __syncthreads();

    // ---- Phase 2: MFMA ----
    int col = lane & 15;
    int kgrp = lane >> 4;
    int e0w = wid * 64;
    f32x4_t acc[2][4];
    #pragma unroll
    for (int a = 0; a < 2; a++)
        #pragma unroll
        for (int b = 0; b < 4; b++) acc[a][b] = (f32x4_t)(0.f);

    #pragma unroll
    for (int kk = 0; kk < 10; kk++) {
        int k0 = kk * 32 + kgrp * 8;
        bf16x8_t afr[2], bfr[4];
        #pragma unroll
        for (int mt = 0; mt < 2; mt++)
            afr[mt] = *(const bf16x8_t*)(&semb[mt * 16 + col][k0]);
        #pragma unroll
        for (int nt = 0; nt < 4; nt++) {
            int e = e0w + nt * 16 + col;
            bfr[nt] = *(const bf16x8_t*)(lin_w_pad + (size_t)e * P_PAD + k0);
        }
        #pragma unroll
        for (int mt = 0; mt < 2; mt++)
            #pragma unroll
            for (int nt = 0; nt < 4; nt++)
                acc[mt][nt] = __builtin_amdgcn_mfma_f32_16x16x32_bf16(
                    afr[mt], bfr[nt], acc[mt][nt], 0, 0, 0);
    }

    // epilogue: + lin_b + regular_w[v2r[0]] (padding regular row for custom tokens)
    int rid0 = v2r[0];
    const float* rrow0 = regular_w + (size_t)rid0 * E_DIM;
    float lb[4];
    #pragma unroll
    for (int nt = 0; nt < 4; nt++) lb[nt] = lin_b[e0w + nt * 16 + col];
    int rbase = (lane >> 4) * 4;   // C/D: col = lane&15, row = (lane>>4)*4 + reg
    #pragma unroll
    for (int mt = 0; mt < 2; mt++) {
        #pragma unroll
        for (int r = 0; r < 4; r++) {
            int i = i0 + mt * 16 + rbase + r;
            if (i < count) {
                int t = list[i];
                float* orow = out + (size_t)t * E_DIM;
                #pragma unroll
                for (int nt = 0; nt < 4; nt++) {
                    int e = e0w + nt * 16 + col;
                    orow[e] = acc[mt][nt][r] + lb[nt] + rrow0[e];
                }
            }
        }
    }
}

extern "C" void kernel_launch(void* const* d_in, const int* in_sizes, int n_in,
                              void* d_out, int out_size, void* d_ws, size_t ws_size,
                              hipStream_t stream) {
    const int* x   = (const int*)d_in[0];
    // d_in[1] = custom_indices (unused; vocab_to_custom[x]!=0 is equivalent to isin)
    const int* v2c = (const int*)d_in[2];
    const int* v2r = (const int*)d_in[3];
    const float* fixed_w   = (const float*)d_in[4];
    const float* train_w   = (const float*)d_in[5];
    const float* regular_w = (const float*)d_in[6];
    const float* lin_w     = (const float*)d_in[7];
    const float* lin_b     = (const float*)d_in[8];
    float* out = (float*)d_out;

    // ws layout (total ~2.26 MB): [counter 256B][info 1MB][list 1MB][lin_w_pad 160KB]
    char* ws = (char*)d_ws;
    int* counter = (int*)ws;
    int* info    = (int*)(ws + 256);
    int* list    = (int*)(ws + 256 + 4 * (size_t)NTOK);
    unsigned short* lin_w_pad = (unsigned short*)(ws + 256 + 8 * (size_t)NTOK);

    hipMemsetAsync(counter, 0, 64, stream);
    k1_classify<<<NTOK / 256, 256, 0, stream>>>(x, v2c, v2r, lin_w,
                                                info, list, counter, lin_w_pad);
    k2_base<<<NTOK / 32, 256, 0, stream>>>(info, regular_w, lin_b, out);
    k3_gemm<<<NTOK / 32, 256, 0, stream>>>(list, counter, info, v2r,
                                           fixed_w, train_w, lin_w_pad,
                                           regular_w, lin_b, out);
}

// Round 4
// 451.880 us; speedup vs baseline: 1.0913x; 1.0913x over previous
//
#include <hip/hip_runtime.h>
#include <stdint.h>
#include <math.h>

#define NTOK (1024 * 256)   // B*L
#define P_DIM 300
#define P_PAD 320           // padded K for MFMA (multiple of 32)
#define P_LDS 328           // LDS row stride in bf16 elems (656B rows, 16B-aligned)
#define E_DIM 256

typedef __attribute__((ext_vector_type(8))) short bf16x8_t;
typedef __attribute__((ext_vector_type(4))) float f32x4_t;

__device__ __forceinline__ unsigned short f2b(float f) {
    union { float f; unsigned int i; } v; v.f = f;
    unsigned int x = v.i;
    return (unsigned short)((x + 0x7FFFu + ((x >> 16) & 1u)) >> 16);  // RNE f32->bf16
}

// K1: classify 4 tokens/thread; ONE atomicAdd per block (256 total), ballot-based
// intra-block compaction into list. info = -cm for custom, ridx for regular.
__global__ __launch_bounds__(256) void k1_classify(
        const int* __restrict__ x, const int* __restrict__ v2c,
        const int* __restrict__ v2r,
        int* __restrict__ info, int* __restrict__ list, int* __restrict__ counter) {
    __shared__ int wb[4];
    int tid = threadIdx.x;
    int wid = tid >> 6;
    int lane = tid & 63;
    int base = blockIdx.x * 1024;

    int cmv[4], tv[4];
    unsigned long long bl[4];
    int wcnt = 0;
    #pragma unroll
    for (int it = 0; it < 4; it++) {
        int t = base + it * 256 + tid;
        int xv = x[t];
        int cm = v2c[xv];                     // mask == (cm != 0)
        cmv[it] = cm; tv[it] = t;
        info[t] = (cm > 0) ? -cm : v2r[xv];
        bl[it] = __ballot(cm > 0);
        wcnt += __popcll(bl[it]);
    }
    if (lane == 0) wb[wid] = wcnt;
    __syncthreads();
    if (tid == 0) {
        int tot = wb[0] + wb[1] + wb[2] + wb[3];
        int b0 = atomicAdd(counter, tot);     // the ONLY global atomic (256/grid)
        int p = b0;
        #pragma unroll
        for (int w = 0; w < 4; w++) { int c = wb[w]; wb[w] = p; p += c; }
    }
    __syncthreads();
    int off = wb[wid];
    unsigned long long lmask = (1ull << lane) - 1ull;
    #pragma unroll
    for (int it = 0; it < 4; it++) {
        if (cmv[it] > 0) {
            int pos = off + __popcll(bl[it] & lmask);
            list[pos] = tv[it];
        }
        off += __popcll(bl[it]);
    }
}

// K2: regular tokens: out = lin_b + regular_w[ridx] (custom rows written by K3).
// One wave per token, one float4 per lane (64 * 16B = full 1KB row).
// First 320 blocks also convert+pad lin_w f32[256,300] -> bf16[256,320].
__global__ __launch_bounds__(256) void k2_base(
        const int* __restrict__ info,
        const float* __restrict__ regular_w,
        const float* __restrict__ lin_b,
        const float* __restrict__ lin_w,
        unsigned short* __restrict__ lin_w_pad,
        float* __restrict__ out) {
    int tid = threadIdx.x;
    if (blockIdx.x < (E_DIM * P_PAD) / 256) {
        int idx = blockIdx.x * 256 + tid;
        int e = idx / P_PAD;
        int k = idx - e * P_PAD;
        lin_w_pad[idx] = (k < P_DIM) ? f2b(lin_w[e * P_DIM + k]) : (unsigned short)0;
    }
    int lane = tid & 63;
    int wq = tid >> 6;
    float4 lb = *(const float4*)(lin_b + lane * 4);
    int base = blockIdx.x * 32;
    #pragma unroll
    for (int it = 0; it < 8; it++) {
        int t = base + wq * 8 + it;
        int inf = info[t];
        if (inf >= 0) {                       // wave-uniform branch (per token)
            float4 rf = *(const float4*)(regular_w + (size_t)inf * E_DIM + lane * 4);
            float4 o;
            o.x = rf.x + lb.x; o.y = rf.y + lb.y;
            o.z = rf.z + lb.z; o.w = rf.w + lb.w;
            *(float4*)(out + (size_t)t * E_DIM + lane * 4) = o;
        }
    }
}

// K3: fused Poincare-emb + MFMA GEMM over compacted custom tokens.
// Block = 256 thr (4 waves), tile = 32 tokens x 256 outputs.
// Phase 1: wave w computes emb (f32) for tokens w*8..w*8+7 -> bf16 into LDS.
// Phase 2: 16x16x32 bf16 MFMA, A from LDS, B (lin_w_pad bf16) from global.
__global__ __launch_bounds__(256) void k3_gemm(
        const int* __restrict__ list, const int* __restrict__ counter,
        const int* __restrict__ info, const int* __restrict__ v2r,
        const float* __restrict__ fixed_w,
        const float* __restrict__ train_w,
        const unsigned short* __restrict__ lin_w_pad,
        const float* __restrict__ regular_w,
        const float* __restrict__ lin_b,
        float* __restrict__ out) {
    __shared__ __align__(16) unsigned short semb[32][P_LDS];
    int count = counter[0];
    int i0 = blockIdx.x * 32;
    if (i0 >= count) return;                  // uniform per block; before any sync
    int tid = threadIdx.x;
    int wid = tid >> 6;
    int lane = tid & 63;

    // ---- Phase 1: embeddings into LDS ----
    for (int it = 0; it < 8; it++) {
        int i = i0 + wid * 8 + it;
        int iS = (i < count) ? i : (count - 1);   // clamp: dup rows never stored
        int t = list[iS];
        int cm = -info[t];                        // listed tokens have info = -cm
        const float* fw = fixed_w + (size_t)cm * P_DIM;
        const float* tw = train_w + (size_t)cm * P_DIM;
        float w[5], tr[5];
        float sw2 = 0.f, st2 = 0.f, swt = 0.f;
        #pragma unroll
        for (int s = 0; s < 5; s++) {
            int j = lane + 64 * s;
            float wv = 0.f, tv = 0.f;
            if (j < P_DIM) { wv = fw[j]; tv = tw[j]; }
            w[s] = wv; tr[s] = tv;
            sw2 = fmaf(wv, wv, sw2); st2 = fmaf(tv, tv, st2); swt = fmaf(wv, tv, swt);
        }
        #pragma unroll
        for (int m = 32; m >= 1; m >>= 1) {
            sw2 += __shfl_xor(sw2, m, 64);
            st2 += __shfl_xor(st2, m, 64);
            swt += __shfl_xor(swt, m, 64);
        }
        float norm = sqrtf(sw2);
        norm = fminf(norm, 0.9999999f);           // defensive: never fires on valid data
        float scale = (norm > 0.f) ? (atanhf(norm) / norm) : 1.0f;
        float x2 = scale * scale * sw2;           // ||logmap0(w)||^2
        float y2 = st2;
        float xy = scale * swt;                   // <logmap0(w), tr>
        float c1 = (1.f + 2.f * xy + y2) * scale; // coeff of w
        float c2 = (1.f - x2);                    // coeff of tr
        float den = fmaxf(1.f + 2.f * xy + x2 * y2, 1e-15f);
        float inv = 1.f / den;
        int tl = wid * 8 + it;
        #pragma unroll
        for (int s = 0; s < 5; s++) {
            int j = lane + 64 * s;                // covers 0..319
            float v = (j < P_DIM) ? (c1 * w[s] + c2 * tr[s]) * inv : 0.f;
            semb[tl][j] = f2b(v);
        }
    }
    __syncthreads();

    // ---- Phase 2: MFMA ----
    int col = lane & 15;
    int kgrp = lane >> 4;
    int e0w = wid * 64;
    f32x4_t acc[2][4];
    #pragma unroll
    for (int a = 0; a < 2; a++)
        #pragma unroll
        for (int b = 0; b < 4; b++) acc[a][b] = (f32x4_t)(0.f);

    #pragma unroll
    for (int kk = 0; kk < 10; kk++) {
        int k0 = kk * 32 + kgrp * 8;
        bf16x8_t afr[2], bfr[4];
        #pragma unroll
        for (int mt = 0; mt < 2; mt++)
            afr[mt] = *(const bf16x8_t*)(&semb[mt * 16 + col][k0]);
        #pragma unroll
        for (int nt = 0; nt < 4; nt++) {
            int e = e0w + nt * 16 + col;
            bfr[nt] = *(const bf16x8_t*)(lin_w_pad + (size_t)e * P_PAD + k0);
        }
        #pragma unroll
        for (int mt = 0; mt < 2; mt++)
            #pragma unroll
            for (int nt = 0; nt < 4; nt++)
                acc[mt][nt] = __builtin_amdgcn_mfma_f32_16x16x32_bf16(
                    afr[mt], bfr[nt], acc[mt][nt], 0, 0, 0);
    }

    // epilogue: + lin_b + regular_w[v2r[0]] (padding regular row for custom tokens)
    int rid0 = v2r[0];
    const float* rrow0 = regular_w + (size_t)rid0 * E_DIM;
    float lb[4];
    #pragma unroll
    for (int nt = 0; nt < 4; nt++) lb[nt] = lin_b[e0w + nt * 16 + col];
    int rbase = (lane >> 4) * 4;   // C/D: col = lane&15, row = (lane>>4)*4 + reg
    #pragma unroll
    for (int mt = 0; mt < 2; mt++) {
        #pragma unroll
        for (int r = 0; r < 4; r++) {
            int i = i0 + mt * 16 + rbase + r;
            if (i < count) {
                int t = list[i];
                float* orow = out + (size_t)t * E_DIM;
                #pragma unroll
                for (int nt = 0; nt < 4; nt++) {
                    int e = e0w + nt * 16 + col;
                    orow[e] = acc[mt][nt][r] + lb[nt] + rrow0[e];
                }
            }
        }
    }
}

extern "C" void kernel_launch(void* const* d_in, const int* in_sizes, int n_in,
                              void* d_out, int out_size, void* d_ws, size_t ws_size,
                              hipStream_t stream) {
    const int* x   = (const int*)d_in[0];
    // d_in[1] = custom_indices (unused; vocab_to_custom[x]!=0 is equivalent to isin)
    const int* v2c = (const int*)d_in[2];
    const int* v2r = (const int*)d_in[3];
    const float* fixed_w   = (const float*)d_in[4];
    const float* train_w   = (const float*)d_in[5];
    const float* regular_w = (const float*)d_in[6];
    const float* lin_w     = (const float*)d_in[7];
    const float* lin_b     = (const float*)d_in[8];
    float* out = (float*)d_out;

    // ws layout (total ~2.26 MB): [counter 256B][info 1MB][list 1MB][lin_w_pad 160KB]
    char* ws = (char*)d_ws;
    int* counter = (int*)ws;
    int* info    = (int*)(ws + 256);
    int* list    = (int*)(ws + 256 + 4 * (size_t)NTOK);
    unsigned short* lin_w_pad = (unsigned short*)(ws + 256 + 8 * (size_t)NTOK);

    hipMemsetAsync(counter, 0, 64, stream);
    k1_classify<<<NTOK / 1024, 256, 0, stream>>>(x, v2c, v2r, info, list, counter);
    k2_base<<<NTOK / 32, 256, 0, stream>>>(info, regular_w, lin_b, lin_w,
                                           lin_w_pad, out);
    k3_gemm<<<NTOK / 32, 256, 0, stream>>>(list, counter, info, v2r,
                                           fixed_w, train_w, lin_w_pad,
                                           regular_w, lin_b, out);
}